// Round 8
// baseline (365.783 us; speedup 1.0000x reference)
//
#include <hip/hip_runtime.h>

#define Bb 32
#define Nn 4096
#define Dd 256
#define Hh 256
#define NCH 32
#define CHUNK 128

typedef __attribute__((ext_vector_type(8))) _Float16 half8;
typedef __attribute__((ext_vector_type(4))) float f32x4;

__device__ __forceinline__ float fast_tanhf(float x) {
    float e = __expf(2.0f * x);
    return 1.0f - 2.0f / (e + 1.0f);
}

__device__ __forceinline__ half8 cvt8(f32x4 v0, f32x4 v1) {
    half8 h;
    h[0] = (_Float16)v0.x; h[1] = (_Float16)v0.y;
    h[2] = (_Float16)v0.z; h[3] = (_Float16)v0.w;
    h[4] = (_Float16)v1.x; h[5] = (_Float16)v1.y;
    h[6] = (_Float16)v1.z; h[7] = (_Float16)v1.w;
    return h;
}

// ---------------------------------------------------------------------------
// Prep: Wcat = [Wq ; Wk] (H=256 rows, K=512 cols) -> f16 blob, fragment-linear:
// Wf[s][j][l][e] = (f16) Wcat[j*16+(l&15)][s*32+(l>>4)*8+e]
// ---------------------------------------------------------------------------
__global__ __launch_bounds__(256) void prep_w_kernel(
    const float* __restrict__ Wq, const float* __restrict__ Wk,
    _Float16* __restrict__ Wf)
{
    const int g = blockIdx.x * 256 + threadIdx.x;      // [0, 16384)
    const int s = g >> 10;
    const int j = (g >> 6) & 15;
    const int l = g & 63;
    const int n = j * 16 + (l & 15);
    const int k = s * 32 + (l >> 4) * 8;
    const float* src = (k < 256) ? (Wq + n * 256 + k) : (Wk + n * 256 + (k - 256));
    const f32x4 v0 = *(const f32x4*)src;
    const f32x4 v1 = *(const f32x4*)(src + 4);
    *(half8*)&Wf[(size_t)g * 8] = cvt8(v0, v1);
}

// ---------------------------------------------------------------------------
// Scores, streaming form. Block = 512 threads (8 waves) x 128 rows.
// Wave w owns h-strip [32w, 32w+32): its full B operand (32 cols x K=512)
// lives in 32 half8 REGISTERS (preloaded once from the L2-resident blob).
// Hot loop per 16-row group: fully unrolled K (16 steps x {2 global A-loads
// (offset-folded), cvt, 2 MFMA}). No LDS, no barriers in the loop -> pure
// HBM stream, latency hidden by 8-wave TLP + unrolled ILP.
// One __syncthreads at the end for the cross-wave h-reduction.
// ---------------------------------------------------------------------------
__global__ __launch_bounds__(512, 2) void scores_stream_kernel(
    const float* __restrict__ Q, const float* __restrict__ Kmat,
    const _Float16* __restrict__ Wf,
    const float* __restrict__ Wv, float* __restrict__ scores)
{
    __shared__ float red[8][128];

    const int tid = threadIdx.x;
    const int lane = tid & 63;
    const int wave = tid >> 6;
    const size_t row0 = (size_t)blockIdx.x * 128;

    // B preload: 32 half8 = 128 VGPR (static indices only; fully unrolled)
    half8 Breg[32];
#pragma unroll
    for (int s = 0; s < 16; ++s) {
        Breg[2 * s]     = *(const half8*)(Wf + ((size_t)(s * 16 + 2 * wave)     * 64 + lane) * 8);
        Breg[2 * s + 1] = *(const half8*)(Wf + ((size_t)(s * 16 + 2 * wave + 1) * 64 + lane) * 8);
    }
    const float wv0 = Wv[wave * 32 + (lane & 15)];
    const float wv1 = Wv[wave * 32 + 16 + (lane & 15)];

    const int rlane = lane & 15;          // row within 16-row group
    const int koff  = (lane >> 4) * 8;    // k-chunk within 32-col window

    for (int rg = 0; rg < 8; ++rg) {
        const float* qb = Q    + (row0 + rg * 16 + rlane) * Dd + koff;
        const float* kb = Kmat + (row0 + rg * 16 + rlane) * Dd + koff;
        f32x4 acc0 = (f32x4){0.f, 0.f, 0.f, 0.f};
        f32x4 acc1 = (f32x4){0.f, 0.f, 0.f, 0.f};
#pragma unroll
        for (int s = 0; s < 16; ++s) {
            const float* p = (s < 8) ? (qb + s * 32) : (kb + (s - 8) * 32);
            const f32x4 v0 = *(const f32x4*)p;
            const f32x4 v1 = *(const f32x4*)(p + 4);
            const half8 a = cvt8(v0, v1);
            acc0 = __builtin_amdgcn_mfma_f32_16x16x32_f16(a, Breg[2 * s],     acc0, 0, 0, 0);
            acc1 = __builtin_amdgcn_mfma_f32_16x16x32_f16(a, Breg[2 * s + 1], acc1, 0, 0, 0);
        }
        // epilogue: per lane, rows r = (lane>>4)*4+i, col = lane&15 (per tile)
        float t[4];
#pragma unroll
        for (int i = 0; i < 4; ++i)
            t[i] = wv0 * fast_tanhf(acc0[i]) + wv1 * fast_tanhf(acc1[i]);
#pragma unroll
        for (int mask = 1; mask <= 8; mask <<= 1)
#pragma unroll
            for (int i = 0; i < 4; ++i)
                t[i] += __shfl_xor(t[i], mask, 64);
        if ((lane & 15) == 0) {
#pragma unroll
            for (int i = 0; i < 4; ++i)
                red[wave][rg * 16 + (lane >> 4) * 4 + i] = t[i];
        }
    }
    __syncthreads();
    if (tid < 128) {
        float s = 0.f;
#pragma unroll
        for (int w = 0; w < 8; ++w) s += red[w][tid];
        scores[row0 + tid] = s;
    }
}

// ---------------------------------------------------------------------------
// Per-b max + argmax + sum(exp). Argmax protected by f64 safety net:
// candidates within tau of max are recomputed exactly (f64 accumulation);
// pick by (exact score, lowest index). Deterministic: the candidate SET is
// data-determined and the (value,index) argmax is order-independent.
// ---------------------------------------------------------------------------
#define MAXC 64
__global__ __launch_bounds__(256) void softmax_reduce_kernel(
    const float* __restrict__ scores,
    const float* __restrict__ Qg, const float* __restrict__ Kg,
    const float* __restrict__ Wq, const float* __restrict__ Wk,
    const float* __restrict__ Wv,
    float* __restrict__ mbuf, float* __restrict__ zbuf, float* __restrict__ out)
{
    __shared__ float sv[256];
    __shared__ int si[256];
    __shared__ double dred[256];
    __shared__ int cand[MAXC];
    __shared__ int cnt;
    const int b = blockIdx.x;
    const int tid = threadIdx.x;
    const float* sc = scores + (size_t)b * Nn;

    // pass 1: max + first-index argmax
    float best = -1e30f; int bi = 0;
    for (int j = 0; j < Nn / 256; ++j) {
        const int n = tid + j * 256;
        const float v = sc[n];
        if (v > best) { best = v; bi = n; }
    }
    sv[tid] = best; si[tid] = bi;
    __syncthreads();
    for (int off = 128; off > 0; off >>= 1) {
        if (tid < off) {
            const float v2 = sv[tid + off]; const int i2 = si[tid + off];
            if (v2 > sv[tid] || (v2 == sv[tid] && i2 < si[tid])) { sv[tid] = v2; si[tid] = i2; }
        }
        __syncthreads();
    }
    const float m = sv[0];
    int amax = si[0];
    __syncthreads();

    // pass 2: sum(exp)
    float ssum = 0.f;
    for (int j = 0; j < Nn / 256; ++j) ssum += __expf(sc[tid + j * 256] - m);
    sv[tid] = ssum;
    __syncthreads();
    for (int off = 128; off > 0; off >>= 1) {
        if (tid < off) sv[tid] += sv[tid + off];
        __syncthreads();
    }
    const float Z = sv[0];
    __syncthreads();

    // safety net: exact argmax among near-max candidates
    if (tid == 0) cnt = 0;
    __syncthreads();
    const float tau = 0.02f;    // >> 5-sigma f16-GEMM score error (~1.4e-3 std)
    for (int j = 0; j < Nn / 256; ++j) {
        const int n = tid + j * 256;
        if (sc[n] >= m - tau) {
            const int p = atomicAdd(&cnt, 1);
            if (p < MAXC) cand[p] = n;
        }
    }
    __syncthreads();
    const int ncand = (cnt < MAXC) ? cnt : MAXC;
    if (ncand > 1) {
        double bestv = -1e300; int besti = 0x7fffffff;
        for (int c = 0; c < ncand; ++c) {
            const int n = cand[c];
            const float* qr = Qg + ((size_t)b * Nn + n) * Dd;
            const float* kr = Kg + ((size_t)b * Nn + n) * Dd;
            const float* wqr = Wq + tid * Dd;
            const float* wkr = Wk + tid * Dd;
            double accd = 0.0;
            for (int k2 = 0; k2 < Dd; ++k2)
                accd += (double)qr[k2] * (double)wqr[k2] + (double)kr[k2] * (double)wkr[k2];
            dred[tid] = (double)Wv[tid] * tanh(accd);
            __syncthreads();
            for (int off = 128; off > 0; off >>= 1) {
                if (tid < off) dred[tid] += dred[tid + off];
                __syncthreads();
            }
            const double s_c = dred[0];
            __syncthreads();
            if (s_c > bestv || (s_c == bestv && n < besti)) { bestv = s_c; besti = n; }
        }
        amax = besti;
    }

    if (tid == 0) {
        mbuf[b] = m;
        zbuf[b] = Z;
        out[(size_t)Bb * Dd + b] = (float)amax;
    }
}

// ---------------------------------------------------------------------------
// Partial out over n-chunks (no atomics; fixed-order accumulation)
// ---------------------------------------------------------------------------
__global__ __launch_bounds__(256) void partial_kernel(
    const float* __restrict__ V, const float* __restrict__ scores,
    const float* __restrict__ mbuf, float* __restrict__ part)
{
    __shared__ float e[CHUNK];
    const int c = blockIdx.x;
    const int b = blockIdx.y;
    const int tid = threadIdx.x;
    const float m = mbuf[b];
    if (tid < CHUNK)
        e[tid] = __expf(scores[(size_t)b * Nn + (size_t)c * CHUNK + tid] - m);
    __syncthreads();

    const float* vp = V + ((size_t)b * Nn + (size_t)c * CHUNK) * Dd + tid;
    float a0 = 0.f, a1 = 0.f, a2 = 0.f, a3 = 0.f;
    for (int n = 0; n < CHUNK; n += 4) {
        a0 = fmaf(e[n + 0], vp[(size_t)(n + 0) * Dd], a0);
        a1 = fmaf(e[n + 1], vp[(size_t)(n + 1) * Dd], a1);
        a2 = fmaf(e[n + 2], vp[(size_t)(n + 2) * Dd], a2);
        a3 = fmaf(e[n + 3], vp[(size_t)(n + 3) * Dd], a3);
    }
    part[((size_t)b * NCH + c) * Dd + tid] = ((a0 + a1) + (a2 + a3));
}

__global__ __launch_bounds__(256) void finalize_kernel(
    const float* __restrict__ part, const float* __restrict__ zbuf,
    float* __restrict__ out)
{
    const int b = blockIdx.x;
    const int tid = threadIdx.x;
    float s = 0.f;
#pragma unroll
    for (int c = 0; c < NCH; ++c) s += part[((size_t)b * NCH + c) * Dd + tid];
    out[(size_t)b * Dd + tid] = s / zbuf[b];
}

extern "C" void kernel_launch(void* const* d_in, const int* in_sizes, int n_in,
                              void* d_out, int out_size, void* d_ws, size_t ws_size,
                              hipStream_t stream) {
    const float* Q  = (const float*)d_in[0];
    const float* K  = (const float*)d_in[1];
    const float* V  = (const float*)d_in[2];
    const float* Wq = (const float*)d_in[3];
    const float* Wk = (const float*)d_in[4];
    const float* Wv = (const float*)d_in[5];
    float* out = (float*)d_out;

    // ws layout (bytes): Wf[256K] | scores[512K] | m[128] | z[128] | part[1M]
    char* wsb = (char*)d_ws;
    _Float16* Wf  = (_Float16*)(wsb);
    float* scores = (float*)(wsb + 262144);
    float* mbuf   = (float*)(wsb + 786432);
    float* zbuf   = (float*)(wsb + 786432 + 128);
    float* part   = (float*)(wsb + 786432 + 256);

    prep_w_kernel<<<dim3(64), dim3(256), 0, stream>>>(Wq, Wk, Wf);
    scores_stream_kernel<<<dim3((Bb * Nn) / 128), dim3(512), 0, stream>>>(Q, K, Wf, Wv, scores);
    softmax_reduce_kernel<<<dim3(Bb), dim3(256), 0, stream>>>(scores, Q, K, Wq, Wk, Wv, mbuf, zbuf, out);
    partial_kernel<<<dim3(NCH, Bb), dim3(256), 0, stream>>>(V, scores, mbuf, part);
    finalize_kernel<<<dim3(Bb), dim3(256), 0, stream>>>(part, zbuf, out);
}

// Round 9
// 149.354 us; speedup vs baseline: 2.4491x; 2.4491x over previous
//
#include <hip/hip_runtime.h>

#define Bb 32
#define Nn 4096
#define Dd 256
#define Hh 256
#define NCH 32
#define CHUNK 128

typedef __attribute__((ext_vector_type(8))) _Float16 half8;
typedef __attribute__((ext_vector_type(4))) float f32x4;

__device__ __forceinline__ float fast_tanhf(float x) {
    float e = __expf(2.0f * x);
    return 1.0f - 2.0f / (e + 1.0f);
}

__device__ __forceinline__ half8 cvt8(f32x4 v0, f32x4 v1) {
    half8 h;
    h[0] = (_Float16)v0.x; h[1] = (_Float16)v0.y;
    h[2] = (_Float16)v0.z; h[3] = (_Float16)v0.w;
    h[4] = (_Float16)v1.x; h[5] = (_Float16)v1.y;
    h[6] = (_Float16)v1.z; h[7] = (_Float16)v1.w;
    return h;
}

// ---------------------------------------------------------------------------
// Prep: Wcat = [Wq ; Wk] (H=256 rows, K=512 cols) -> f16 blob, fragment-linear:
// Wf[gs][j][l][e] = (f16) Wcat[j*16+(l&15)][gs*32+(l>>4)*8+e],  gs in [0,16)
// ---------------------------------------------------------------------------
__global__ __launch_bounds__(256) void prep_w_kernel(
    const float* __restrict__ Wq, const float* __restrict__ Wk,
    _Float16* __restrict__ Wf)
{
    const int g = blockIdx.x * 256 + threadIdx.x;      // [0, 16384)
    const int s = g >> 10;
    const int j = (g >> 6) & 15;
    const int l = g & 63;
    const int n = j * 16 + (l & 15);
    const int k = s * 32 + (l >> 4) * 8;
    const float* src = (k < 256) ? (Wq + n * 256 + k) : (Wk + n * 256 + (k - 256));
    const f32x4 v0 = *(const f32x4*)src;
    const f32x4 v1 = *(const f32x4*)(src + 4);
    *(half8*)&Wf[(size_t)g * 8] = cvt8(v0, v1);
}

// ---------------------------------------------------------------------------
// Scores. Block = 64 rows x 256 h, 4 waves; wave w owns cols [64w,64w+64):
// m=4 row-tiles x n=4 col-tiles, 16x16x32 f16 MFMA. BK=64 (8 K-steps).
// Per step: load B (L2, 8 frags) -> issue A(s+1) (HBM) -> MFMA (waits B only,
// vmcnt(4)) -> cvt+store A(s+1) to LDS[(s+1)&1] -> __syncthreads.
// Small register/LDS footprint => 3+ blocks/CU co-resident: one block's
// load-drain stall hides under the other blocks' MFMA.
// ---------------------------------------------------------------------------
__global__ __launch_bounds__(256, 3) void scores_tile_kernel(
    const float* __restrict__ Q, const float* __restrict__ Kmat,
    const _Float16* __restrict__ Wf,
    const float* __restrict__ Wv, float* __restrict__ scores)
{
    __shared__ _Float16 Abuf[2][4096];   // [buf][slot*8]; slot = kk*256+m*64+l  (8 KB each)
    __shared__ float red[4][64];

    const int tid = threadIdx.x;
    const int lane = tid & 63;
    const int wave = tid >> 6;
    const size_t row0 = (size_t)blockIdx.x * 64;

    f32x4 acc[4][4];
#pragma unroll
    for (int m = 0; m < 4; ++m)
#pragma unroll
        for (int n = 0; n < 4; ++n) acc[m][n] = (f32x4){0.f, 0.f, 0.f, 0.f};

    float wv[4];
#pragma unroll
    for (int n = 0; n < 4; ++n) wv[n] = Wv[wave * 64 + n * 16 + (lane & 15)];

    // staging: thread t owns slots t (kk=0) and t+256 (kk=1).
    // slot = kk*256 + m*64 + l: row = m*16+(l&15), k = kk*32+(l>>4)*8.
    const int srow = ((tid >> 6) << 4) + (tid & 15);   // = m*16+(l&15), m=wave
    const int skf  = ((tid >> 4) & 3) * 8;             // float offset in 32-k half

    f32x4 a0, a1, a2, a3;     // staged A (one step ahead)
    half8 BB[8];              // B frags for current step (kk-major)

    auto issue_a = [&](int s) {
        const float* base = (s < 4)
            ? (Q    + (row0 + srow) * Dd + s * 64)
            : (Kmat + (row0 + srow) * Dd + (s - 4) * 64);
        const float* p0 = base + skf;
        const float* p1 = base + 32 + skf;
        a0 = *(const f32x4*)p0; a1 = *(const f32x4*)(p0 + 4);
        a2 = *(const f32x4*)p1; a3 = *(const f32x4*)(p1 + 4);
    };
    auto store_a = [&](int buf) {
        *(half8*)&Abuf[buf][tid * 8] = cvt8(a0, a1);
        *(half8*)&Abuf[buf][(tid + 256) * 8] = cvt8(a2, a3);
    };
    auto issue_b = [&](int s) {
#pragma unroll
        for (int kk = 0; kk < 2; ++kk)
#pragma unroll
            for (int n = 0; n < 4; ++n)
                BB[kk * 4 + n] = *(const half8*)(Wf +
                    ((size_t)((s * 2 + kk) * 16 + wave * 4 + n) * 64 + lane) * 8);
    };
    auto cluster = [&](int buf) {
        __builtin_amdgcn_s_setprio(1);
#pragma unroll
        for (int kk = 0; kk < 2; ++kk)
#pragma unroll
            for (int m = 0; m < 4; ++m) {
                const half8 a = *(const half8*)&Abuf[buf][(kk * 256 + m * 64 + lane) * 8];
#pragma unroll
                for (int n = 0; n < 4; ++n)
                    acc[m][n] = __builtin_amdgcn_mfma_f32_16x16x32_f16(a, BB[kk * 4 + n], acc[m][n], 0, 0, 0);
            }
        __builtin_amdgcn_s_setprio(0);
    };

    // prologue
    issue_a(0);
    store_a(0);
    __syncthreads();

    for (int s = 0; s < 8; ++s) {
        issue_b(s);                       // L2 loads, consumed by this step's MFMA
        if (s < 7) issue_a(s + 1);        // HBM loads, consumed after MFMA
        cluster(s & 1);                   // waits vmcnt(4): B done, A in flight
        if (s < 7) store_a((s + 1) & 1);  // waits A; had the MFMA window to land
        __syncthreads();
    }

    // Epilogue: score_row += Wv[col]*tanh(acc). C/D: col = lane&15,
    // row = m*16+(lane>>4)*4+r. Fixed-order reduce -> deterministic.
    const int q = lane >> 4;
    float rp[4][4];
#pragma unroll
    for (int m = 0; m < 4; ++m)
#pragma unroll
        for (int r = 0; r < 4; ++r) {
            float v = 0.f;
#pragma unroll
            for (int n = 0; n < 4; ++n)
                v += wv[n] * fast_tanhf(acc[m][n][r]);
            rp[m][r] = v;
        }
#pragma unroll
    for (int mask = 1; mask <= 8; mask <<= 1)
#pragma unroll
        for (int m = 0; m < 4; ++m)
#pragma unroll
            for (int r = 0; r < 4; ++r)
                rp[m][r] += __shfl_xor(rp[m][r], mask, 64);

    if ((lane & 15) == 0) {
#pragma unroll
        for (int m = 0; m < 4; ++m)
#pragma unroll
            for (int r = 0; r < 4; ++r)
                red[wave][m * 16 + q * 4 + r] = rp[m][r];
    }
    __syncthreads();
    if (tid < 64)
        scores[row0 + tid] = (red[0][tid] + red[1][tid]) + (red[2][tid] + red[3][tid]);
}

// ---------------------------------------------------------------------------
// Per-b max + argmax + sum(exp). Argmax protected by f64 safety net:
// candidates within tau of max are recomputed exactly (f64 accumulation);
// pick by (exact score, lowest index). Deterministic: candidate SET is
// data-determined and the (value,index) argmax is order-independent.
// ---------------------------------------------------------------------------
#define MAXC 64
__global__ __launch_bounds__(256) void softmax_reduce_kernel(
    const float* __restrict__ scores,
    const float* __restrict__ Qg, const float* __restrict__ Kg,
    const float* __restrict__ Wq, const float* __restrict__ Wk,
    const float* __restrict__ Wv,
    float* __restrict__ mbuf, float* __restrict__ zbuf, float* __restrict__ out)
{
    __shared__ float sv[256];
    __shared__ int si[256];
    __shared__ double dred[256];
    __shared__ int cand[MAXC];
    __shared__ int cnt;
    const int b = blockIdx.x;
    const int tid = threadIdx.x;
    const float* sc = scores + (size_t)b * Nn;

    float best = -1e30f; int bi = 0;
    for (int j = 0; j < Nn / 256; ++j) {
        const int n = tid + j * 256;
        const float v = sc[n];
        if (v > best) { best = v; bi = n; }
    }
    sv[tid] = best; si[tid] = bi;
    __syncthreads();
    for (int off = 128; off > 0; off >>= 1) {
        if (tid < off) {
            const float v2 = sv[tid + off]; const int i2 = si[tid + off];
            if (v2 > sv[tid] || (v2 == sv[tid] && i2 < si[tid])) { sv[tid] = v2; si[tid] = i2; }
        }
        __syncthreads();
    }
    const float m = sv[0];
    int amax = si[0];
    __syncthreads();

    float ssum = 0.f;
    for (int j = 0; j < Nn / 256; ++j) ssum += __expf(sc[tid + j * 256] - m);
    sv[tid] = ssum;
    __syncthreads();
    for (int off = 128; off > 0; off >>= 1) {
        if (tid < off) sv[tid] += sv[tid + off];
        __syncthreads();
    }
    const float Z = sv[0];
    __syncthreads();

    if (tid == 0) cnt = 0;
    __syncthreads();
    const float tau = 0.02f;    // >> 5-sigma f16-GEMM score error (~1.4e-3 std)
    for (int j = 0; j < Nn / 256; ++j) {
        const int n = tid + j * 256;
        if (sc[n] >= m - tau) {
            const int p = atomicAdd(&cnt, 1);
            if (p < MAXC) cand[p] = n;
        }
    }
    __syncthreads();
    const int ncand = (cnt < MAXC) ? cnt : MAXC;
    if (ncand > 1) {
        double bestv = -1e300; int besti = 0x7fffffff;
        for (int c = 0; c < ncand; ++c) {
            const int n = cand[c];
            const float* qr = Qg + ((size_t)b * Nn + n) * Dd;
            const float* kr = Kg + ((size_t)b * Nn + n) * Dd;
            const float* wqr = Wq + tid * Dd;
            const float* wkr = Wk + tid * Dd;
            double accd = 0.0;
            for (int k2 = 0; k2 < Dd; ++k2)
                accd += (double)qr[k2] * (double)wqr[k2] + (double)kr[k2] * (double)wkr[k2];
            dred[tid] = (double)Wv[tid] * tanh(accd);
            __syncthreads();
            for (int off = 128; off > 0; off >>= 1) {
                if (tid < off) dred[tid] += dred[tid + off];
                __syncthreads();
            }
            const double s_c = dred[0];
            __syncthreads();
            if (s_c > bestv || (s_c == bestv && n < besti)) { bestv = s_c; besti = n; }
        }
        amax = besti;
    }

    if (tid == 0) {
        mbuf[b] = m;
        zbuf[b] = Z;
        out[(size_t)Bb * Dd + b] = (float)amax;
    }
}

// ---------------------------------------------------------------------------
// Partial out over n-chunks (no atomics; fixed-order accumulation)
// ---------------------------------------------------------------------------
__global__ __launch_bounds__(256) void partial_kernel(
    const float* __restrict__ V, const float* __restrict__ scores,
    const float* __restrict__ mbuf, float* __restrict__ part)
{
    __shared__ float e[CHUNK];
    const int c = blockIdx.x;
    const int b = blockIdx.y;
    const int tid = threadIdx.x;
    const float m = mbuf[b];
    if (tid < CHUNK)
        e[tid] = __expf(scores[(size_t)b * Nn + (size_t)c * CHUNK + tid] - m);
    __syncthreads();

    const float* vp = V + ((size_t)b * Nn + (size_t)c * CHUNK) * Dd + tid;
    float a0 = 0.f, a1 = 0.f, a2 = 0.f, a3 = 0.f;
    for (int n = 0; n < CHUNK; n += 4) {
        a0 = fmaf(e[n + 0], vp[(size_t)(n + 0) * Dd], a0);
        a1 = fmaf(e[n + 1], vp[(size_t)(n + 1) * Dd], a1);
        a2 = fmaf(e[n + 2], vp[(size_t)(n + 2) * Dd], a2);
        a3 = fmaf(e[n + 3], vp[(size_t)(n + 3) * Dd], a3);
    }
    part[((size_t)b * NCH + c) * Dd + tid] = ((a0 + a1) + (a2 + a3));
}

__global__ __launch_bounds__(256) void finalize_kernel(
    const float* __restrict__ part, const float* __restrict__ zbuf,
    float* __restrict__ out)
{
    const int b = blockIdx.x;
    const int tid = threadIdx.x;
    float s = 0.f;
#pragma unroll
    for (int c = 0; c < NCH; ++c) s += part[((size_t)b * NCH + c) * Dd + tid];
    out[(size_t)b * Dd + tid] = s / zbuf[b];
}

extern "C" void kernel_launch(void* const* d_in, const int* in_sizes, int n_in,
                              void* d_out, int out_size, void* d_ws, size_t ws_size,
                              hipStream_t stream) {
    const float* Q  = (const float*)d_in[0];
    const float* K  = (const float*)d_in[1];
    const float* V  = (const float*)d_in[2];
    const float* Wq = (const float*)d_in[3];
    const float* Wk = (const float*)d_in[4];
    const float* Wv = (const float*)d_in[5];
    float* out = (float*)d_out;

    // ws layout (bytes): Wf[256K] | scores[512K] | m[128] | z[128] | part[1M]
    char* wsb = (char*)d_ws;
    _Float16* Wf  = (_Float16*)(wsb);
    float* scores = (float*)(wsb + 262144);
    float* mbuf   = (float*)(wsb + 786432);
    float* zbuf   = (float*)(wsb + 786432 + 128);
    float* part   = (float*)(wsb + 786432 + 256);

    prep_w_kernel<<<dim3(64), dim3(256), 0, stream>>>(Wq, Wk, Wf);
    scores_tile_kernel<<<dim3((Bb * Nn) / 64), dim3(256), 0, stream>>>(Q, K, Wf, Wv, scores);
    softmax_reduce_kernel<<<dim3(Bb), dim3(256), 0, stream>>>(scores, Q, K, Wq, Wk, Wv, mbuf, zbuf, out);
    partial_kernel<<<dim3(NCH, Bb), dim3(256), 0, stream>>>(V, scores, mbuf, part);
    finalize_kernel<<<dim3(Bb), dim3(256), 0, stream>>>(part, zbuf, out);
}

// Round 10
// 146.296 us; speedup vs baseline: 2.5003x; 1.0209x over previous
//
#include <hip/hip_runtime.h>

#define Bb 32
#define Nn 4096
#define Dd 256
#define Hh 256
#define NCH 32
#define CHUNK 128

typedef __attribute__((ext_vector_type(8))) _Float16 half8;
typedef __attribute__((ext_vector_type(4))) float f32x4;

// direct global->LDS DMA, 16 B per lane; gp per-lane, lp wave-uniform
#define GLDS16(gp, lp) __builtin_amdgcn_global_load_lds( \
    (const __attribute__((address_space(1))) unsigned int*)(gp), \
    (__attribute__((address_space(3))) unsigned int*)(lp), 16, 0, 0)

__device__ __forceinline__ float fast_tanhf(float x) {
    float e = __expf(2.0f * x);
    return 1.0f - 2.0f / (e + 1.0f);
}

__device__ __forceinline__ half8 cvt8(f32x4 v0, f32x4 v1) {
    half8 h;
    h[0] = (_Float16)v0.x; h[1] = (_Float16)v0.y;
    h[2] = (_Float16)v0.z; h[3] = (_Float16)v0.w;
    h[4] = (_Float16)v1.x; h[5] = (_Float16)v1.y;
    h[6] = (_Float16)v1.z; h[7] = (_Float16)v1.w;
    return h;
}

// ---------------------------------------------------------------------------
// Prep: Wcat = [Wq ; Wk] (H=256 rows, K=512 cols) -> f16 blob, fragment-linear:
// Wf[gs][j][l][e] = (f16) Wcat[j*16+(l&15)][gs*32+(l>>4)*8+e],  gs in [0,16)
// ---------------------------------------------------------------------------
__global__ __launch_bounds__(256) void prep_w_kernel(
    const float* __restrict__ Wq, const float* __restrict__ Wk,
    _Float16* __restrict__ Wf)
{
    const int g = blockIdx.x * 256 + threadIdx.x;      // [0, 16384)
    const int s = g >> 10;
    const int j = (g >> 6) & 15;
    const int l = g & 63;
    const int n = j * 16 + (l & 15);
    const int k = s * 32 + (l >> 4) * 8;
    const float* src = (k < 256) ? (Wq + n * 256 + k) : (Wk + n * 256 + (k - 256));
    const f32x4 v0 = *(const f32x4*)src;
    const f32x4 v1 = *(const f32x4*)(src + 4);
    *(half8*)&Wf[(size_t)g * 8] = cvt8(v0, v1);
}

// ---------------------------------------------------------------------------
// Scores. Block = 64 rows x 256 h, 4 waves; wave w owns cols [64w,64w+64):
// m=4 x n=4 tiles of 16x16x32 f16 MFMA, BK=64 (8 K-steps).
// A staged by global_load_lds DMA into FRAGMENT-LINEAR f32 LDS:
//   slot = kk*256 + m*64 + lane holds f32[8] of (row=m*16+(lane&15),
//   k = kk*32 + (lane>>4)*8). DMA writes linearly (base+lane*16); the
//   per-lane GLOBAL address is pre-permuted so fragment order lands
//   naturally (per-issue: 16 rows x 64 B contiguous -> coalesced).
// No A registers, no ds_write: cvt f32->f16 happens at fragment load.
// B frags from L2-resident Wf blob each step.
// ---------------------------------------------------------------------------
__global__ __launch_bounds__(256, 3) void scores_dma_kernel(
    const float* __restrict__ Q, const float* __restrict__ Kmat,
    const _Float16* __restrict__ Wf,
    const float* __restrict__ Wv, float* __restrict__ scores)
{
    __shared__ float Abuf[2][4096];    // 16 KB per buffer, frag-linear
    __shared__ float red[4][64];

    const int tid = threadIdx.x;
    const int lane = tid & 63;
    const int wave = tid >> 6;
    const size_t row0 = (size_t)blockIdx.x * 64;

    f32x4 acc[4][4];
#pragma unroll
    for (int m = 0; m < 4; ++m)
#pragma unroll
        for (int n = 0; n < 4; ++n) acc[m][n] = (f32x4){0.f, 0.f, 0.f, 0.f};

    float wv[4];
#pragma unroll
    for (int n = 0; n < 4; ++n) wv[n] = Wv[wave * 64 + n * 16 + (lane & 15)];

    // Per-thread DMA gather offsets (f32 elements), one per issue j=0..3.
    // Issue i = wave*4+j covers slots [i*32, i*32+32); lane l supplies the
    // 16 B for slot i*32+(l>>1), half (l&1):
    //   kk = i>>3, m = (i>>1)&3, row = m*16+((l>>1)&15),
    //   k = kk*32 + ((i&1)*2 + (l>>5))*8 + (l&1)*4
    int eoff[4];
#pragma unroll
    for (int j = 0; j < 4; ++j) {
        const int i = wave * 4 + j;
        const int kk = i >> 3;
        const int m  = (i >> 1) & 3;
        const int row_local = m * 16 + ((lane >> 1) & 15);
        const int kloc = kk * 32 + ((i & 1) * 2 + (lane >> 5)) * 8 + (lane & 1) * 4;
        eoff[j] = row_local * Dd + kloc;
    }

    half8 BB[8];
    auto issue_b = [&](int s) {
#pragma unroll
        for (int kk = 0; kk < 2; ++kk)
#pragma unroll
            for (int n = 0; n < 4; ++n)
                BB[kk * 4 + n] = *(const half8*)(Wf +
                    ((size_t)((s * 2 + kk) * 16 + wave * 4 + n) * 64 + lane) * 8);
    };
    auto dma_a = [&](int buf, int s) {
        const float* base = (s < 4) ? (Q    + row0 * Dd + s * 64)
                                    : (Kmat + row0 * Dd + (s - 4) * 64);
        char* lbase = (char*)&Abuf[buf][0] + wave * 4096;
#pragma unroll
        for (int j = 0; j < 4; ++j)
            GLDS16(base + eoff[j], lbase + j * 1024);
    };
    auto cluster = [&](int buf) {
        __builtin_amdgcn_s_setprio(1);
#pragma unroll
        for (int kk = 0; kk < 2; ++kk)
#pragma unroll
            for (int m = 0; m < 4; ++m) {
                const float* fp = &Abuf[buf][(kk * 256 + m * 64 + lane) * 8];
                const f32x4 lo = *(const f32x4*)fp;
                const f32x4 hi = *(const f32x4*)(fp + 4);
                const half8 a = cvt8(lo, hi);
#pragma unroll
                for (int n = 0; n < 4; ++n)
                    acc[m][n] = __builtin_amdgcn_mfma_f32_16x16x32_f16(a, BB[kk * 4 + n], acc[m][n], 0, 0, 0);
            }
        __builtin_amdgcn_s_setprio(0);
    };

    // prologue: DMA step 0 into buf0 (drained by the barrier)
    dma_a(0, 0);
    __syncthreads();

    for (int s = 0; s < 8; ++s) {
        issue_b(s);                       // L2 loads, consumed by this step's MFMA
        if (s < 7) dma_a((s + 1) & 1, s + 1);   // HBM DMA for next step
        cluster(s & 1);                   // waits B (counted vmcnt); DMA in flight
        __syncthreads();                  // drains DMA -> next buffer ready
    }

    // Epilogue: score_row += Wv[col]*tanh(acc). C/D: col = lane&15,
    // row = m*16+(lane>>4)*4+r. Fixed-order reduce -> deterministic.
    const int q = lane >> 4;
    float rp[4][4];
#pragma unroll
    for (int m = 0; m < 4; ++m)
#pragma unroll
        for (int r = 0; r < 4; ++r) {
            float v = 0.f;
#pragma unroll
            for (int n = 0; n < 4; ++n)
                v += wv[n] * fast_tanhf(acc[m][n][r]);
            rp[m][r] = v;
        }
#pragma unroll
    for (int mask = 1; mask <= 8; mask <<= 1)
#pragma unroll
        for (int m = 0; m < 4; ++m)
#pragma unroll
            for (int r = 0; r < 4; ++r)
                rp[m][r] += __shfl_xor(rp[m][r], mask, 64);

    if ((lane & 15) == 0) {
#pragma unroll
        for (int m = 0; m < 4; ++m)
#pragma unroll
            for (int r = 0; r < 4; ++r)
                red[wave][m * 16 + q * 4 + r] = rp[m][r];
    }
    __syncthreads();
    if (tid < 64)
        scores[row0 + tid] = (red[0][tid] + red[1][tid]) + (red[2][tid] + red[3][tid]);
}

// ---------------------------------------------------------------------------
// Per-b max + argmax + sum(exp). Argmax protected by f64 safety net:
// candidates within tau of max are recomputed exactly (f64 accumulation);
// pick by (exact score, lowest index). Deterministic: candidate SET is
// data-determined and the (value,index) argmax is order-independent.
// ---------------------------------------------------------------------------
#define MAXC 64
__global__ __launch_bounds__(256) void softmax_reduce_kernel(
    const float* __restrict__ scores,
    const float* __restrict__ Qg, const float* __restrict__ Kg,
    const float* __restrict__ Wq, const float* __restrict__ Wk,
    const float* __restrict__ Wv,
    float* __restrict__ mbuf, float* __restrict__ zbuf, float* __restrict__ out)
{
    __shared__ float sv[256];
    __shared__ int si[256];
    __shared__ double dred[256];
    __shared__ int cand[MAXC];
    __shared__ int cnt;
    const int b = blockIdx.x;
    const int tid = threadIdx.x;
    const float* sc = scores + (size_t)b * Nn;

    float best = -1e30f; int bi = 0;
    for (int j = 0; j < Nn / 256; ++j) {
        const int n = tid + j * 256;
        const float v = sc[n];
        if (v > best) { best = v; bi = n; }
    }
    sv[tid] = best; si[tid] = bi;
    __syncthreads();
    for (int off = 128; off > 0; off >>= 1) {
        if (tid < off) {
            const float v2 = sv[tid + off]; const int i2 = si[tid + off];
            if (v2 > sv[tid] || (v2 == sv[tid] && i2 < si[tid])) { sv[tid] = v2; si[tid] = i2; }
        }
        __syncthreads();
    }
    const float m = sv[0];
    int amax = si[0];
    __syncthreads();

    float ssum = 0.f;
    for (int j = 0; j < Nn / 256; ++j) ssum += __expf(sc[tid + j * 256] - m);
    sv[tid] = ssum;
    __syncthreads();
    for (int off = 128; off > 0; off >>= 1) {
        if (tid < off) sv[tid] += sv[tid + off];
        __syncthreads();
    }
    const float Z = sv[0];
    __syncthreads();

    if (tid == 0) cnt = 0;
    __syncthreads();
    const float tau = 0.02f;    // >> 5-sigma f16-GEMM score error (~1.4e-3 std)
    for (int j = 0; j < Nn / 256; ++j) {
        const int n = tid + j * 256;
        if (sc[n] >= m - tau) {
            const int p = atomicAdd(&cnt, 1);
            if (p < MAXC) cand[p] = n;
        }
    }
    __syncthreads();
    const int ncand = (cnt < MAXC) ? cnt : MAXC;
    if (ncand > 1) {
        double bestv = -1e300; int besti = 0x7fffffff;
        for (int c = 0; c < ncand; ++c) {
            const int n = cand[c];
            const float* qr = Qg + ((size_t)b * Nn + n) * Dd;
            const float* kr = Kg + ((size_t)b * Nn + n) * Dd;
            const float* wqr = Wq + tid * Dd;
            const float* wkr = Wk + tid * Dd;
            double accd = 0.0;
            for (int k2 = 0; k2 < Dd; ++k2)
                accd += (double)qr[k2] * (double)wqr[k2] + (double)kr[k2] * (double)wkr[k2];
            dred[tid] = (double)Wv[tid] * tanh(accd);
            __syncthreads();
            for (int off = 128; off > 0; off >>= 1) {
                if (tid < off) dred[tid] += dred[tid + off];
                __syncthreads();
            }
            const double s_c = dred[0];
            __syncthreads();
            if (s_c > bestv || (s_c == bestv && n < besti)) { bestv = s_c; besti = n; }
        }
        amax = besti;
    }

    if (tid == 0) {
        mbuf[b] = m;
        zbuf[b] = Z;
        out[(size_t)Bb * Dd + b] = (float)amax;
    }
}

// ---------------------------------------------------------------------------
// Partial out over n-chunks (no atomics; fixed-order accumulation)
// ---------------------------------------------------------------------------
__global__ __launch_bounds__(256) void partial_kernel(
    const float* __restrict__ V, const float* __restrict__ scores,
    const float* __restrict__ mbuf, float* __restrict__ part)
{
    __shared__ float e[CHUNK];
    const int c = blockIdx.x;
    const int b = blockIdx.y;
    const int tid = threadIdx.x;
    const float m = mbuf[b];
    if (tid < CHUNK)
        e[tid] = __expf(scores[(size_t)b * Nn + (size_t)c * CHUNK + tid] - m);
    __syncthreads();

    const float* vp = V + ((size_t)b * Nn + (size_t)c * CHUNK) * Dd + tid;
    float a0 = 0.f, a1 = 0.f, a2 = 0.f, a3 = 0.f;
    for (int n = 0; n < CHUNK; n += 4) {
        a0 = fmaf(e[n + 0], vp[(size_t)(n + 0) * Dd], a0);
        a1 = fmaf(e[n + 1], vp[(size_t)(n + 1) * Dd], a1);
        a2 = fmaf(e[n + 2], vp[(size_t)(n + 2) * Dd], a2);
        a3 = fmaf(e[n + 3], vp[(size_t)(n + 3) * Dd], a3);
    }
    part[((size_t)b * NCH + c) * Dd + tid] = ((a0 + a1) + (a2 + a3));
}

__global__ __launch_bounds__(256) void finalize_kernel(
    const float* __restrict__ part, const float* __restrict__ zbuf,
    float* __restrict__ out)
{
    const int b = blockIdx.x;
    const int tid = threadIdx.x;
    float s = 0.f;
#pragma unroll
    for (int c = 0; c < NCH; ++c) s += part[((size_t)b * NCH + c) * Dd + tid];
    out[(size_t)b * Dd + tid] = s / zbuf[b];
}

extern "C" void kernel_launch(void* const* d_in, const int* in_sizes, int n_in,
                              void* d_out, int out_size, void* d_ws, size_t ws_size,
                              hipStream_t stream) {
    const float* Q  = (const float*)d_in[0];
    const float* K  = (const float*)d_in[1];
    const float* V  = (const float*)d_in[2];
    const float* Wq = (const float*)d_in[3];
    const float* Wk = (const float*)d_in[4];
    const float* Wv = (const float*)d_in[5];
    float* out = (float*)d_out;

    // ws layout (bytes): Wf[256K] | scores[512K] | m[128] | z[128] | part[1M]
    char* wsb = (char*)d_ws;
    _Float16* Wf  = (_Float16*)(wsb);
    float* scores = (float*)(wsb + 262144);
    float* mbuf   = (float*)(wsb + 786432);
    float* zbuf   = (float*)(wsb + 786432 + 128);
    float* part   = (float*)(wsb + 786432 + 256);

    prep_w_kernel<<<dim3(64), dim3(256), 0, stream>>>(Wq, Wk, Wf);
    scores_dma_kernel<<<dim3((Bb * Nn) / 64), dim3(256), 0, stream>>>(Q, K, Wf, Wv, scores);
    softmax_reduce_kernel<<<dim3(Bb), dim3(256), 0, stream>>>(scores, Q, K, Wq, Wk, Wv, mbuf, zbuf, out);
    partial_kernel<<<dim3(NCH, Bb), dim3(256), 0, stream>>>(V, scores, mbuf, part);
    finalize_kernel<<<dim3(Bb), dim3(256), 0, stream>>>(part, zbuf, out);
}